// Round 1
// baseline (68.734 us; speedup 1.0000x reference)
//
#include <hip/hip_runtime.h>

// QLSTM collapses analytically:
//   quantum_gate(x, p)[:, i] = prod_{j<=i} cos(p_j) * cos(x_j)   (i < 4 -> only
//   input wires, hx never affects the gates). LSTM becomes, per (b,h):
//   cx_t = f_t*cx_{t-1} + i_t*g_t ;  hx_t = o_t*tanh(cx_t)
// with f/i/o = sigmoid(C_h * m_h), g = tanh(Cg_h * m_h),
// m_h = cumprod cos(x[t,b,0..h]), C_h = cumprod cos(params[0..h]).
//
// Parallel over T via linear-recurrence segment scan:
//   block = 16 batches x 32 time-slots (4 t each) = 512 threads, grid = 256.

#define T_STEPS 128
#define BATCH   4096
#define NB      16   // batches per block
#define NT      32   // time slots per block (covers T = NT*KT)
#define KT      4    // timesteps per thread

__device__ __forceinline__ float rcp_fast(float x) { return __builtin_amdgcn_rcpf(x); }
__device__ __forceinline__ float sigm(float x) { return rcp_fast(1.0f + __expf(-x)); }
__device__ __forceinline__ float tanh_fast(float x) {
    float e = __expf(2.0f * x);
    return (e - 1.0f) * rcp_fast(e + 1.0f);
}

__global__ __launch_bounds__(NB * NT) void qlstm_kernel(
    const float* __restrict__ X,   // [T, B, 4]
    const float* __restrict__ pf,
    const float* __restrict__ pi,
    const float* __restrict__ pg,
    const float* __restrict__ po,
    float* __restrict__ out)       // outputs [T,B,4] ++ hx [B,4] ++ cx [B,4]
{
    const int tid  = threadIdx.x;
    const int bl   = tid & (NB - 1);
    const int slot = tid / NB;               // 0..NT-1
    const int b    = blockIdx.x * NB + bl;   // global batch
    const int t0   = slot * KT;

    // Per-gate cumulative-cos constants (wires 0..3 only)
    float CF[4], CI[4], CG[4], CO[4];
    {
        float a = 1.f, c = 1.f, g = 1.f, o = 1.f;
#pragma unroll
        for (int j = 0; j < 4; ++j) {
            a *= __cosf(pf[j]); CF[j] = a;
            c *= __cosf(pi[j]); CI[j] = c;
            g *= __cosf(pg[j]); CG[j] = g;
            o *= __cosf(po[j]); CO[j] = o;
        }
    }

    const float4* Xv = (const float4*)X;

    // Pass 1: compute per-step f, u=i*g, o; compose segment transform (A,U)
    float4 fr[KT], ur[KT], orr[KT];
    float Ax = 1.f, Ay = 1.f, Az = 1.f, Aw = 1.f;
    float Ux = 0.f, Uy = 0.f, Uz = 0.f, Uw = 0.f;

#pragma unroll
    for (int k = 0; k < KT; ++k) {
        const int t = t0 + k;
        float4 xv = Xv[t * BATCH + b];
        float c0 = __cosf(xv.x);
        float c1 = __cosf(xv.y);
        float c2 = __cosf(xv.z);
        float c3 = __cosf(xv.w);
        float m0 = c0, m1 = m0 * c1, m2 = m1 * c2, m3 = m2 * c3;

        float4 f, i4, g4, o4;
        f.x  = sigm(CF[0] * m0);  f.y  = sigm(CF[1] * m1);
        f.z  = sigm(CF[2] * m2);  f.w  = sigm(CF[3] * m3);
        i4.x = sigm(CI[0] * m0);  i4.y = sigm(CI[1] * m1);
        i4.z = sigm(CI[2] * m2);  i4.w = sigm(CI[3] * m3);
        g4.x = tanh_fast(CG[0] * m0);  g4.y = tanh_fast(CG[1] * m1);
        g4.z = tanh_fast(CG[2] * m2);  g4.w = tanh_fast(CG[3] * m3);
        o4.x = sigm(CO[0] * m0);  o4.y = sigm(CO[1] * m1);
        o4.z = sigm(CO[2] * m2);  o4.w = sigm(CO[3] * m3);

        float4 u;
        u.x = i4.x * g4.x; u.y = i4.y * g4.y;
        u.z = i4.z * g4.z; u.w = i4.w * g4.w;

        // compose: state' = f*state + u applied AFTER current (A,U)
        Ux = f.x * Ux + u.x;  Uy = f.y * Uy + u.y;
        Uz = f.z * Uz + u.z;  Uw = f.w * Uw + u.w;
        Ax *= f.x;  Ay *= f.y;  Az *= f.z;  Aw *= f.w;

        fr[k] = f; ur[k] = u; orr[k] = o4;
    }

    // Segment scan across the 32 time slots (per b, per h) in LDS.
    // Layout [slot][h*16 + bl]; +1 pad column keeps conflicts <= 2-way (free).
    __shared__ float sA[NT][65];
    __shared__ float sU[NT][65];
    sA[slot][bl]      = Ax;  sU[slot][bl]      = Ux;
    sA[slot][16 + bl] = Ay;  sU[slot][16 + bl] = Uy;
    sA[slot][32 + bl] = Az;  sU[slot][32 + bl] = Uz;
    sA[slot][48 + bl] = Aw;  sU[slot][48 + bl] = Uw;
    __syncthreads();

    if (tid < 64) {
        // lane tid owns column (h*16+b); serial exclusive scan over 32 slots
        float acc = 0.f;  // cx = 0 at t = -1
#pragma unroll
        for (int s = 0; s < NT; ++s) {
            float a = sA[s][tid];
            float u = sU[s][tid];
            sU[s][tid] = acc;          // cx entering slot s
            acc = a * acc + u;
        }
    }
    __syncthreads();

    float cxx = sU[slot][bl];
    float cxy = sU[slot][16 + bl];
    float cxz = sU[slot][32 + bl];
    float cxw = sU[slot][48 + bl];

    // Replay: emit hx for each t
    float4* outv = (float4*)out;
    float4 hx;
#pragma unroll
    for (int k = 0; k < KT; ++k) {
        const int t = t0 + k;
        cxx = fr[k].x * cxx + ur[k].x;
        cxy = fr[k].y * cxy + ur[k].y;
        cxz = fr[k].z * cxz + ur[k].z;
        cxw = fr[k].w * cxw + ur[k].w;
        hx.x = orr[k].x * tanh_fast(cxx);
        hx.y = orr[k].y * tanh_fast(cxy);
        hx.z = orr[k].z * tanh_fast(cxz);
        hx.w = orr[k].w * tanh_fast(cxw);
        outv[t * BATCH + b] = hx;
    }

    if (slot == NT - 1) {
        // final hx, cx (t = 127)
        outv[T_STEPS * BATCH + b] = hx;
        float4 cxv; cxv.x = cxx; cxv.y = cxy; cxv.z = cxz; cxv.w = cxw;
        outv[T_STEPS * BATCH + BATCH + b] = cxv;
    }
}

extern "C" void kernel_launch(void* const* d_in, const int* in_sizes, int n_in,
                              void* d_out, int out_size, void* d_ws, size_t ws_size,
                              hipStream_t stream) {
    const float* X  = (const float*)d_in[0];
    const float* pf = (const float*)d_in[1];
    const float* pi = (const float*)d_in[2];
    const float* pg = (const float*)d_in[3];
    const float* po = (const float*)d_in[4];
    float* out = (float*)d_out;

    dim3 grid(BATCH / NB);       // 256 blocks
    dim3 block(NB * NT);         // 512 threads = 8 waves
    qlstm_kernel<<<grid, block, 0, stream>>>(X, pf, pi, pg, po, out);
}